// Round 13
// baseline (1751.892 us; speedup 1.0000x reference)
//
#include <hip/hip_runtime.h>
#include <math.h>

// Problem constants
constexpr int Bb = 64;    // batch
constexpr int Pp = 400;   // passage len
constexpr int Qq = 50;    // question len
constexpr int Ee = 300;   // embed dim
constexpr int Hh = 256;   // hidden
constexpr int H3 = 768;   // 3*H
constexpr int Dd = 512;   // 2*H

#define NEGC (-10000000.0f)
#define LOGTINY (-103.278929903f)   // log(float32(1e-45)) = log(2^-149)

typedef _Float16 h2 __attribute__((ext_vector_type(2)));
typedef _Float16 f16x8 __attribute__((ext_vector_type(8)));
typedef float f32x4 __attribute__((ext_vector_type(4)));

__device__ __forceinline__ float allred(float v){
  #pragma unroll
  for (int off = 1; off < 64; off <<= 1) v += __shfl_xor(v, off);
  return v;
}
__device__ __forceinline__ float allmax(float v){
  #pragma unroll
  for (int off = 1; off < 64; off <<= 1) v = fmaxf(v, __shfl_xor(v, off));
  return v;
}
__device__ __forceinline__ float sigm(float x){ return 1.f / (1.f + expf(-x)); }

__device__ __forceinline__ float dot2f(unsigned a, unsigned b, float c){
#if __has_builtin(__builtin_amdgcn_fdot2)
  return __builtin_amdgcn_fdot2(__builtin_bit_cast(h2, a), __builtin_bit_cast(h2, b), c, false);
#else
  float r = c;
  asm("v_dot2_f32_f16 %0, %1, %2, %0" : "+v"(r) : "v"(a), "v"(b));
  return r;
#endif
}

#define U4C(v,c) ((c)==0?(v).x:((c)==1?(v).y:((c)==2?(v).z:(v).w)))

// ---------------------------------------------------------------------------
// prep_emb16: emb fp32 [V][300] -> fp16 [V][320] zero-padded (16B-aligned rows)
// ---------------------------------------------------------------------------
__global__ __launch_bounds__(256) void prep_emb16(const float* __restrict__ emb,
                                                  _Float16* __restrict__ emb16){
  size_t idx = (size_t)blockIdx.x * 256 + threadIdx.x;   // pair id
  if (idx >= (size_t)100000 * 160) return;
  int col2 = (int)(idx % 160);
  size_t row = idx / 160;
  int c = col2 * 2;
  float2 v = make_float2(0.f, 0.f);
  if (c < Ee) v = *(const float2*)(emb + row * Ee + c);
  h2 o = { (_Float16)v.x, (_Float16)v.y };
  *(h2*)(emb16 + row * 320 + c) = o;
}

// ---------------------------------------------------------------------------
// prep_wih16: Wih fp32 [g][d][768][300] -> fp16 [g][d][768][320] padded
// ---------------------------------------------------------------------------
__global__ __launch_bounds__(256) void prep_wih16(const float* __restrict__ pW,
                                                  const float* __restrict__ qW,
                                                  _Float16* __restrict__ wih16){
  int idx = blockIdx.x * 256 + threadIdx.x;   // pair id: 2*2*768*160
  if (idx >= 2 * 2 * 768 * 160) return;
  int col2 = idx % 160;
  int r = idx / 160;           // g*1536 + d*768 + h
  int g = r / 1536;
  int dh = r % 1536;           // d*768+h
  int c = col2 * 2;
  const float* W = g ? qW : pW;
  float2 v = make_float2(0.f, 0.f);
  if (c < Ee) v = *(const float2*)(W + (size_t)dh * Ee + c);
  h2 o = { (_Float16)v.x, (_Float16)v.y };
  *(h2*)(wih16 + (size_t)r * 320 + c) = o;
}

// ---------------------------------------------------------------------------
// Pack Whh to fp16 pairs for the 256-thread owner-unit 3-tier layout.
// Per gd: 96 uint4 blocks x 256 threads. Thread j owns hidden unit j
// (rows j, 256+j, 512+j). Block b:
//   b in [0,30):  R tier: g=b/10,      pairs p = 4*(b%10)+c      (0..39)
//   b in [30,66): L tier: g=(b-30)/12, pairs p = 40+4*((b-30)%12)+c (40..87)
//   b in [66,96): S tier: i=(b-66)/3, g=(b-66)%3, p = 88+4*i+c   (88..127)
// slot = ((gd*96 + b)*256 + j)*4 + c ; value = pack(W[d][row][2p], [2p+1]).
// ---------------------------------------------------------------------------
__global__ __launch_bounds__(256) void prep_w16(const float* __restrict__ pW,
                                                const float* __restrict__ qW,
                                                unsigned* __restrict__ w16){
  int idx = blockIdx.x * 256 + threadIdx.x;   // u32 slot id (393216 total)
  if (idx >= 4 * 96 * 256 * 4) return;
  int c = idx & 3;
  int j = (idx >> 2) & 255;
  int rest = idx >> 10;
  int b = rest % 96;
  int gd = rest / 96;
  int d = gd & 1, kind = gd >> 1;
  int g, p;
  if (b < 30){ g = b / 10; p = 4 * (b % 10) + c; }
  else if (b < 66){ int v = b - 30; g = v / 12; p = 40 + 4 * (v % 12) + c; }
  else { int v = b - 66; int i = v / 3; g = v % 3; p = 88 + 4 * i + c; }
  int row = g * 256 + j;
  const float* W = kind ? qW : pW;
  const float* src = W + ((size_t)d * H3 + row) * Hh + 2 * p;
  _Float16 a = (_Float16)src[0], bb = (_Float16)src[1];
  unsigned short ua, ub;
  __builtin_memcpy(&ua, &a, 2); __builtin_memcpy(&ub, &bb, 2);
  w16[idx] = (unsigned)ua | ((unsigned)ub << 16);
}

// ---------------------------------------------------------------------------
// xproj via MFMA, all-fp16 inputs (r12, unchanged)
// ---------------------------------------------------------------------------
__global__ __launch_bounds__(512) void xproj_mfma(const int* __restrict__ tok,
                                                  const _Float16* __restrict__ emb16,
                                                  const _Float16* __restrict__ wih16,
                                                  const float* __restrict__ bih,
                                                  _Float16* __restrict__ xp, int T){
  __shared__ __align__(16) _Float16 Af[128][72];
  __shared__ __align__(16) _Float16 Bf[128][72];
  int tid = threadIdx.x;
  int m0 = blockIdx.y * 128;
  int nt = blockIdx.x;                 // 0..11
  int d = nt / 6, h0 = (nt % 6) * 128;
  int wid = tid >> 6, lane = tid & 63;
  int wr = wid >> 2, wc = wid & 3;

  int r0 = tid >> 3;                    // 0..63
  int r1 = (tid + 512) >> 3;            // 64..127
  int cc = (tid & 7) * 8;               // fp16 col of 8-chunk
  const _Float16* eA0 = emb16 + (size_t)tok[m0 + r0] * 320;
  const _Float16* eA1 = emb16 + (size_t)tok[m0 + r1] * 320;
  const _Float16* wB0 = wih16 + ((size_t)d * H3 + h0 + r0) * 320;
  const _Float16* wB1 = wih16 + ((size_t)d * H3 + h0 + r1) * 320;

  f32x4 acc[4][2] = {};

  for (int k0 = 0; k0 < 320; k0 += 64){
    *(f16x8*)&Af[r0][cc] = *(const f16x8*)(eA0 + k0 + cc);
    *(f16x8*)&Af[r1][cc] = *(const f16x8*)(eA1 + k0 + cc);
    *(f16x8*)&Bf[r0][cc] = *(const f16x8*)(wB0 + k0 + cc);
    *(f16x8*)&Bf[r1][cc] = *(const f16x8*)(wB1 + k0 + cc);
    __syncthreads();
    #pragma unroll
    for (int kc = 0; kc < 2; ++kc){
      int kb = kc * 32 + (lane >> 4) * 8;
      f16x8 af[4], bf[2];
      #pragma unroll
      for (int i = 0; i < 4; ++i) af[i] = *(const f16x8*)&Af[wr * 64 + i * 16 + (lane & 15)][kb];
      #pragma unroll
      for (int jn = 0; jn < 2; ++jn) bf[jn] = *(const f16x8*)&Bf[wc * 32 + jn * 16 + (lane & 15)][kb];
      #pragma unroll
      for (int i = 0; i < 4; ++i)
        #pragma unroll
        for (int jn = 0; jn < 2; ++jn)
          acc[i][jn] = __builtin_amdgcn_mfma_f32_16x16x32_f16(af[i], bf[jn], acc[i][jn], 0, 0, 0);
    }
    __syncthreads();
  }

  #pragma unroll
  for (int jn = 0; jn < 2; ++jn){
    int h = h0 + wc * 32 + jn * 16 + (lane & 15);
    float bv = bih[d * H3 + h];
    #pragma unroll
    for (int i = 0; i < 4; ++i){
      #pragma unroll
      for (int r = 0; r < 4; ++r){
        int m = m0 + wr * 64 + i * 16 + (lane >> 4) * 4 + r;
        int bI = m / T, tI = m - bI * T;
        xp[(((size_t)d * Bb + bI) * T + tI) * H3 + h] = (_Float16)(acc[i][jn][r] + bv);
      }
    }
  }
}

// ---------------------------------------------------------------------------
// 3-tier GRU, 256 threads/WG (owner-unit). 256 WGs x 256 threads.
// Thread j owns hidden unit j: all 3 gate rows. Tiers: 120 u32 in regs,
// 144 u32 in LDS (147 KB -> 1 WG/CU), 120 u32 streamed per step in 10
// groups-of-3 interleaved with compute. Gates thread-local: 1 barrier/step.
// Allocator-budget rationale: at 256 thr the allocator grants ~208 VGPR
// (r5 measured); this design peaks ~195.
// ---------------------------------------------------------------------------
__global__ __launch_bounds__(256, 1)
void gru_kernel(const int* __restrict__ ptok,
                const int* __restrict__ qtok,
                const _Float16* __restrict__ xpp,
                const _Float16* __restrict__ xpq,
                const unsigned* __restrict__ w16,
                const float* __restrict__ pbhh,
                const float* __restrict__ qbhh,
                float* __restrict__ Hp,
                float* __restrict__ Hq){
  int wg = blockIdx.x;
  bool isp = wg < 128;
  int lw = isp ? wg : wg - 128;
  int d = lw & 1, b = lw >> 1;
  int T = isp ? Pp : Qq;
  const int* tok = (isp ? ptok : qtok) + b * T;
  const _Float16* xrow = (isp ? xpp : xpq) + ((size_t)d * Bb + b) * T * H3;
  int gd = (isp ? 0 : 2) + d;
  const float* bhh = (isp ? pbhh : qbhh) + d * H3;
  float* Hout = (isp ? Hp : Hq) + (size_t)b * T * Dd + d * Hh;

  __shared__ __align__(16) uint4 ldsW[36 * 256];   // 147456 B
  __shared__ unsigned hbuf[2][128];                // packed fp16 h

  int j = threadIdx.x, lane = j & 63;
  const uint4* wq = (const uint4*)w16 + (size_t)gd * 96 * 256;

  // R tier: 30 quads -> wr[120]; gate g = quad/10
  unsigned wr[120];
  #pragma unroll
  for (int bq = 0; bq < 30; ++bq){
    uint4 v = wq[bq * 256 + j];
    wr[4 * bq + 0] = v.x; wr[4 * bq + 1] = v.y; wr[4 * bq + 2] = v.z; wr[4 * bq + 3] = v.w;
  }
  #pragma unroll
  for (int i = 0; i < 120; ++i) asm volatile("" : "+v"(wr[i]));

  // L tier -> LDS
  #pragma unroll
  for (int bq = 0; bq < 36; ++bq) ldsW[bq * 256 + j] = wq[(30 + bq) * 256 + j];
  const uint4* wS = wq + 66 * 256;

  float bh0 = bhh[j], bh1 = bhh[Hh + j], bh2 = bhh[2 * Hh + j];
  float h_old = 0.f;
  if (j < 128) hbuf[1][j] = 0u;     // step 0 reads buf[1]
  __syncthreads();

  int t0 = d ? (T - 1) : 0;
  float pre0 = (float)xrow[(size_t)t0 * H3 + j];
  float pre1 = (float)xrow[(size_t)t0 * H3 + Hh + j];
  float pre2 = (float)xrow[(size_t)t0 * H3 + 2 * Hh + j];

  for (int s = 0; s < T; ++s){
    int tt = d ? (T - 1 - s) : s;
    const unsigned* hb = hbuf[(s + 1) & 1];
    unsigned vh0 = hb[lane];
    unsigned vh1 = hb[64 + lane];
    float a0 = 0.f, a1 = 0.f, a2 = 0.f;

    // L-phase macro: quad q of each gate from LDS, shared readlane
    #define LPH(q) { \
      uint4 l0 = ldsW[(q) * 256 + j]; \
      uint4 l1 = ldsW[(12 + (q)) * 256 + j]; \
      uint4 l2 = ldsW[(24 + (q)) * 256 + j]; \
      _Pragma("unroll") \
      for (int c = 0; c < 4; ++c){ \
        int p = 40 + 4 * (q) + c; \
        unsigned hv = (unsigned)__builtin_amdgcn_readlane((int)(p < 64 ? vh0 : vh1), p & 63); \
        a0 = dot2f(U4C(l0, c), hv, a0); \
        a1 = dot2f(U4C(l1, c), hv, a1); \
        a2 = dot2f(U4C(l2, c), hv, a2); } }
    // S-consume macro: group i (pairs 88+4i..91+4i), all >=64 -> vh1
    #define SCON(i, A, B, C) { \
      _Pragma("unroll") \
      for (int c = 0; c < 4; ++c){ \
        unsigned hv = (unsigned)__builtin_amdgcn_readlane((int)vh1, 24 + 4 * (i) + c); \
        a0 = dot2f(U4C(A, c), hv, a0); \
        a1 = dot2f(U4C(B, c), hv, a1); \
        a2 = dot2f(U4C(C, c), hv, a2); } }
    #define SISS(i, A, B, C) \
      uint4 A = wS[((i) * 3 + 0) * 256 + j]; \
      uint4 B = wS[((i) * 3 + 1) * 256 + j]; \
      uint4 C = wS[((i) * 3 + 2) * 256 + j];

    SISS(0, g0a, g0b, g0c)
    SISS(1, g1a, g1b, g1c)

    // R phase: pairs 0..39, shared readlane across 3 gates
    #pragma unroll
    for (int q = 0; q < 10; ++q)
      #pragma unroll
      for (int c = 0; c < 4; ++c){
        unsigned hv = (unsigned)__builtin_amdgcn_readlane((int)vh0, 4 * q + c);
        a0 = dot2f(wr[q * 4 + c], hv, a0);
        a1 = dot2f(wr[40 + q * 4 + c], hv, a1);
        a2 = dot2f(wr[80 + q * 4 + c], hv, a2);
      }

    SISS(2, g2a, g2b, g2c)
    SISS(3, g3a, g3b, g3c)
    LPH(0) LPH(1) LPH(2)
    SCON(0, g0a, g0b, g0c)
    SISS(4, g4a, g4b, g4c)
    SISS(5, g5a, g5b, g5c)
    LPH(3) LPH(4) LPH(5)
    SCON(1, g1a, g1b, g1c)
    SISS(6, g6a, g6b, g6c)
    SISS(7, g7a, g7b, g7c)
    LPH(6) LPH(7) LPH(8)
    SCON(2, g2a, g2b, g2c)
    SISS(8, g8a, g8b, g8c)
    SISS(9, g9a, g9b, g9c)
    LPH(9) LPH(10) LPH(11)
    SCON(3, g3a, g3b, g3c)
    SCON(4, g4a, g4b, g4c)
    SCON(5, g5a, g5b, g5c)
    SCON(6, g6a, g6b, g6c)
    SCON(7, g7a, g7b, g7c)
    SCON(8, g8a, g8b, g8c)
    SCON(9, g9a, g9b, g9c)
    #undef LPH
    #undef SCON
    #undef SISS

    float xt0 = pre0, xt1 = pre1, xt2 = pre2;
    if (s + 1 < T){
      int tn = d ? (T - 2 - s) : (s + 1);
      pre0 = (float)xrow[(size_t)tn * H3 + j];
      pre1 = (float)xrow[(size_t)tn * H3 + Hh + j];
      pre2 = (float)xrow[(size_t)tn * H3 + 2 * Hh + j];
    }
    float r = sigm(xt0 + a0 + bh0);
    float z = sigm(xt1 + a1 + bh1);
    float n = tanhf(xt2 + r * (a2 + bh2));
    float hnew = (1.f - z) * n + z * h_old;
    float m = (tok[tt] != 0) ? 1.f : 0.f;
    float hm = m * hnew + (1.f - m) * h_old;
    h_old = hm;
    ((_Float16*)hbuf[s & 1])[j] = (_Float16)hm;
    Hout[(size_t)tt * Dd + j] = hm * m;
    __syncthreads();
  }
}

// ---------------------------------------------------------------------------
// Attention + logits (unchanged)
// ---------------------------------------------------------------------------
__global__ __launch_bounds__(512) void attn_kernel(const float* __restrict__ Hp,
                                                   const float* __restrict__ Hq,
                                                   const int* __restrict__ ptok,
                                                   const int* __restrict__ qtok,
                                                   const float* __restrict__ start_w,
                                                   const float* __restrict__ sbp,
                                                   const float* __restrict__ end_w,
                                                   const float* __restrict__ ebp,
                                                   float* __restrict__ out){
  extern __shared__ __align__(16) float lds[];
  float* hqs = lds;               // 50*512
  float* s2s = hqs + Qq * Dd;     // 64
  float* qms = s2s + 64;          // 64
  float* scw = qms + 64;          // 8*64
  float* aw  = scw + 512;         // 8*64

  int b = blockIdx.y, pc = blockIdx.x;
  int tid = threadIdx.x, wid = tid >> 6, lane = tid & 63;
  float sb = sbp[0], eb = ebp[0];

  float w1r[8], w2r[8], w3r[8], e1r[8], e2r[8], e3r[8];
  #pragma unroll
  for (int i = 0; i < 8; ++i){
    int c = lane * 8 + i;
    w1r[i] = start_w[c]; w2r[i] = start_w[Dd + c]; w3r[i] = start_w[2 * Dd + c];
    e1r[i] = end_w[c];   e2r[i] = end_w[Dd + c];   e3r[i] = end_w[2 * Dd + c];
  }
  for (int idx = tid; idx < Qq * Dd; idx += 512) hqs[idx] = Hq[(size_t)b * Qq * Dd + idx];
  __syncthreads();

  for (int q = wid; q < Qq; q += 8){
    float part = 0.f;
    const float* hq = hqs + q * Dd + lane * 8;
    #pragma unroll
    for (int i = 0; i < 8; ++i) part += hq[i] * w2r[i];
    part = allred(part);
    if (lane == 0){
      s2s[q] = part;
      qms[q] = (qtok[b * Qq + q] != 0) ? 1.f : 0.f;
    }
  }
  __syncthreads();

  for (int p = pc * 100 + wid; p < pc * 100 + 100; p += 8){
    const float* hprow = Hp + ((size_t)b * Pp + p) * Dd + lane * 8;
    float4 hv0 = *(const float4*)hprow;
    float4 hv1 = *(const float4*)(hprow + 4);
    float hpc[8] = {hv0.x, hv0.y, hv0.z, hv0.w, hv1.x, hv1.y, hv1.z, hv1.w};
    float hw3[8], he3[8];
    float s1 = 0.f, ed = 0.f;
    #pragma unroll
    for (int i = 0; i < 8; ++i){
      hw3[i] = hpc[i] * w3r[i];
      he3[i] = hpc[i] * e3r[i];
      s1 += hpc[i] * w1r[i];
      ed += hpc[i] * e1r[i];
    }
    #pragma unroll
    for (int off = 1; off < 64; off <<= 1){
      s1 += __shfl_xor(s1, off);
      ed += __shfl_xor(ed, off);
    }
    for (int q = 0; q < Qq; ++q){
      const float4* hq4 = (const float4*)(hqs + q * Dd + lane * 8);
      float4 a0 = hq4[0], a1 = hq4[1];
      float dot = hw3[0] * a0.x + hw3[1] * a0.y + hw3[2] * a0.z + hw3[3] * a0.w
                + hw3[4] * a1.x + hw3[5] * a1.y + hw3[6] * a1.z + hw3[7] * a1.w;
      dot = allred(dot);
      if (lane == 0) scw[wid * 64 + q] = (s1 + s2s[q] + dot + sb) * qms[q];
    }
    float v = (lane < Qq) ? scw[wid * 64 + lane] : -1e30f;
    float M = allmax(v);
    float ev = (lane < Qq) ? expf(v - M) : 0.f;
    float S = allred(ev);
    float am = (lane < Qq) ? (ev / S) * qms[lane] : 0.f;
    float Sm = allred(am);
    float af = am / (Sm + 1e-13f);
    if (lane < Qq) aw[wid * 64 + lane] = af;
    float wv[8] = {0.f, 0.f, 0.f, 0.f, 0.f, 0.f, 0.f, 0.f};
    for (int q = 0; q < Qq; ++q){
      float aq = aw[wid * 64 + q];
      const float4* hq4 = (const float4*)(hqs + q * Dd + lane * 8);
      float4 a0 = hq4[0], a1 = hq4[1];
      wv[0] += aq * a0.x; wv[1] += aq * a0.y; wv[2] += aq * a0.z; wv[3] += aq * a0.w;
      wv[4] += aq * a1.x; wv[5] += aq * a1.y; wv[6] += aq * a1.z; wv[7] += aq * a1.w;
    }
    float acc2 = 0.f, acc3 = 0.f, acc4 = 0.f, acc5 = 0.f;
    #pragma unroll
    for (int i = 0; i < 8; ++i){
      acc2 += wv[i] * w2r[i];
      acc3 += hw3[i] * wv[i];
      acc4 += wv[i] * e2r[i];
      acc5 += he3[i] * wv[i];
    }
    #pragma unroll
    for (int off = 1; off < 64; off <<= 1){
      acc2 += __shfl_xor(acc2, off);
      acc3 += __shfl_xor(acc3, off);
      acc4 += __shfl_xor(acc4, off);
      acc5 += __shfl_xor(acc5, off);
    }
    if (lane == 0){
      bool pm = (ptok[b * Pp + p] != 0);
      out[(size_t)b * Pp + p]                   = pm ? (s1 + acc2 + acc3 + sb) : NEGC;
      out[(size_t)Bb * Pp + (size_t)b * Pp + p] = pm ? (ed + acc4 + acc5 + eb) : NEGC;
    }
  }
}

// ---------------------------------------------------------------------------
// log_softmax over p (unchanged)
// ---------------------------------------------------------------------------
__global__ __launch_bounds__(512) void lsm_kernel(const int* __restrict__ ptok,
                                                  float* __restrict__ out){
  int b = blockIdx.x >> 1, sel = blockIdx.x & 1;
  const float* lg = out + (size_t)sel * Bb * Pp + (size_t)b * Pp;
  float* o = out + (size_t)(2 + sel) * Bb * Pp + (size_t)b * Pp;
  int tid = threadIdx.x;
  __shared__ float red1[8];
  __shared__ float red2[8];
  float x = -1e30f;
  if (tid < Pp) x = lg[tid] + ((ptok[b * Pp + tid] != 0) ? 0.f : LOGTINY);
  float m = allmax(x);
  if ((tid & 63) == 0) red1[tid >> 6] = m;
  __syncthreads();
  float M = red1[0];
  #pragma unroll
  for (int i = 1; i < 8; ++i) M = fmaxf(M, red1[i]);
  float e = (tid < Pp) ? expf(x - M) : 0.f;
  float s = allred(e);
  if ((tid & 63) == 0) red2[tid >> 6] = s;
  __syncthreads();
  float S = 0.f;
  #pragma unroll
  for (int i = 0; i < 8; ++i) S += red2[i];
  if (tid < Pp) o[tid] = (x - M) - logf(S);
}

// ---------------------------------------------------------------------------
extern "C" void kernel_launch(void* const* d_in, const int* in_sizes, int n_in,
                              void* d_out, int out_size, void* d_ws, size_t ws_size,
                              hipStream_t stream){
  const int*   passage  = (const int*)d_in[0];
  const int*   question = (const int*)d_in[1];
  const float* emb      = (const float*)d_in[2];
  const float* pW_ih    = (const float*)d_in[3];
  const float* pW_hh    = (const float*)d_in[4];
  const float* pb_ih    = (const float*)d_in[5];
  const float* pb_hh    = (const float*)d_in[6];
  const float* qW_ih    = (const float*)d_in[7];
  const float* qW_hh    = (const float*)d_in[8];
  const float* qb_ih    = (const float*)d_in[9];
  const float* qb_hh    = (const float*)d_in[10];
  const float* start_w  = (const float*)d_in[11];
  const float* start_b  = (const float*)d_in[12];
  const float* end_w    = (const float*)d_in[13];
  const float* end_b    = (const float*)d_in[14];
  float* out = (float*)d_out;

  // workspace layout (float-sized units)
  float*     ws    = (float*)d_ws;
  unsigned*  w16   = (unsigned*)ws;                    //   393216 u32
  _Float16*  emb16 = (_Float16*)(ws + 393216);         // 32,000,000 halfs
  _Float16*  wih16 = (_Float16*)(ws + 16393216);       //   983040 halfs
  _Float16*  xpp   = (_Float16*)(ws + 16884736);       // 39321600 halfs
  _Float16*  xpq   = (_Float16*)(ws + 36545536);       //  4915200 halfs
  float*     Hp    = ws + 39003136;                    // 13107200 f
  float*     Hq    = ws + 52110336;                    //  1638400 f
  // total 53,748,736 floats = 215 MB

  hipLaunchKernelGGL(prep_w16, dim3(1536), dim3(256), 0, stream, pW_hh, qW_hh, w16);
  hipLaunchKernelGGL(prep_emb16, dim3(62500), dim3(256), 0, stream, emb, emb16);
  hipLaunchKernelGGL(prep_wih16, dim3(1920), dim3(256), 0, stream, pW_ih, qW_ih, wih16);
  hipLaunchKernelGGL(xproj_mfma, dim3(12, 200), dim3(512), 0, stream,
                     passage, emb16, wih16, pb_ih, xpp, Pp);
  hipLaunchKernelGGL(xproj_mfma, dim3(12, 25), dim3(512), 0, stream,
                     question, emb16, wih16 + (size_t)2 * H3 * 320, qb_ih, xpq, Qq);
  hipLaunchKernelGGL(gru_kernel, dim3(256), dim3(256), 0, stream,
                     passage, question, xpp, xpq, w16, pb_hh, qb_hh, Hp, Hq);
  size_t attn_lds = (size_t)(Qq * Dd + 64 + 64 + 512 + 512) * sizeof(float);
  hipLaunchKernelGGL(attn_kernel, dim3(4, 64), dim3(512), attn_lds, stream,
                     Hp, Hq, passage, question, start_w, start_b, end_w, end_b, out);
  hipLaunchKernelGGL(lsm_kernel, dim3(128), dim3(512), 0, stream, passage, out);
}